// Round 5
// baseline (162.575 us; speedup 1.0000x reference)
//
#include <hip/hip_runtime.h>
#include <cstdint>

// Problem dims (fixed by the reference)
#define B_DIM 16
#define T_DIM 1024
#define DK    512     // D_IN
#define H_DIM 1024
#define BST   516     // padded LDS leading dim for Bs (bank spread)

typedef __bf16 bf16x8 __attribute__((ext_vector_type(8)));
typedef __bf16 bf16x4 __attribute__((ext_vector_type(4)));
typedef float  f32x4  __attribute__((ext_vector_type(4)));

// ---- fp32 -> bf16 conversion, 4 elems/thread ----
__global__ __launch_bounds__(256) void cvt_f32_bf16(const float* __restrict__ in,
                                                    __bf16* __restrict__ out, int n4) {
  int i = blockIdx.x * 256 + threadIdx.x;
  if (i >= n4) return;
  f32x4 v = ((const f32x4*)in)[i];
  bf16x4 o;
  o.x = (__bf16)v.x; o.y = (__bf16)v.y; o.z = (__bf16)v.z; o.w = (__bf16)v.w;
  ((bf16x4*)out)[i] = o;
}

// ---- per-h meta: {a, log2|a|, neg?, zero-mask?} ----
__global__ __launch_bounds__(256) void compute_meta(const float* __restrict__ raw_a,
                                                    float4* __restrict__ meta) {
  int h = blockIdx.x * 256 + threadIdx.x;
  if (h >= H_DIM) return;
  float a = tanhf(raw_a[h]);
  float la2 = log2f(fabsf(a));   // a==0 -> -inf; exp2f(-inf)=0, handled by zero-mask
  meta[h] = make_float4(a, la2, (a < 0.f) ? 1.f : 0.f, (fabsf(a) < 1e-6f) ? 1.f : 0.f);
}

// ---- fully fused: GEMM (z = x W^T + b) + weighted cumsum scan + output ----
// Grid: 512 blocks = (b = bid&15) x (strip = bid>>4, 32 cols).
// Block: 512 thr, 8 waves. B-strip (32 cols x full K=512) preloaded to LDS ONCE;
// K-loop is BARRIER-FREE: A frags loaded global->VGPR (L2-resident, b%8-pinned
// XCD), B frags from resident LDS. Compiler pipelines A loads with fine vmcnt.
// 4 sequential m-chunks of 256 t; wave w owns rows [w*32, w*32+32).
__global__ __launch_bounds__(512, 4) void fused_rnn(const __bf16* __restrict__ xb,  // [B*T, DK]
                                                    const __bf16* __restrict__ wb,  // [H, DK]
                                                    const float* __restrict__ bias, // [H]
                                                    const float4* __restrict__ meta,// [H]
                                                    const float* __restrict__ h0g,  // [B, H]
                                                    float* __restrict__ out) {      // [B*T, H]
  __shared__ __align__(16) __bf16 Bs[32][BST];   // 33 KB, whole K extent
  __shared__ float chunkTot[8][32];
  __shared__ float colCarry[2][32];

  const int tid  = threadIdx.x;
  const int wave = tid >> 6;   // 0..7
  const int lane = tid & 63;
  const int q = lane >> 4;     // 0..3
  const int c = lane & 15;     // 0..15

  const int b  = blockIdx.x & 15;
  const int n0 = (blockIdx.x >> 4) * 32;

  // per-lane column constants (2 cols per lane: j*16+c)
  float bias_j[2], la2_j[2], h0_j[2];
  bool neg_j[2], zm_j[2];
#pragma unroll
  for (int j = 0; j < 2; ++j) {
    const int col = n0 + j * 16 + c;
    bias_j[j] = bias[col];
    const float4 mt = meta[col];
    la2_j[j] = mt.y;
    neg_j[j] = mt.z != 0.f;
    zm_j[j]  = mt.w != 0.f;
    h0_j[j]  = h0g[(size_t)b * H_DIM + col];
  }

  // preload whole B strip: 512 thr = 32 cols x 16 k-chunks of 32
  {
    const int col = tid >> 4;
    const int kc  = tid & 15;
    const __bf16* gw = wb + (size_t)(n0 + col) * DK + kc * 32;
#pragma unroll
    for (int u = 0; u < 4; ++u)
      *(bf16x8*)&Bs[col][kc * 32 + u * 8] = *(const bf16x8*)(gw + u * 8);
  }
  if (tid < 32) colCarry[0][tid] = 0.f;
  __syncthreads();   // the ONLY barrier before the scan epilogues

  const __bf16* const xbB = xb + (size_t)b * T_DIM * DK;

  for (int mc = 0; mc < 4; ++mc) {
    const int t0 = mc * 256;

    f32x4 acc[2][2];
#pragma unroll
    for (int i = 0; i < 2; ++i)
#pragma unroll
      for (int j = 0; j < 2; ++j) acc[i][j] = (f32x4){0.f, 0.f, 0.f, 0.f};

    // barrier-free K-loop: A direct from global (L2), B from resident LDS
    const __bf16* const Arow0 = xbB + (size_t)(t0 + wave * 32 + c) * DK + q * 8;
    const __bf16* const Arow1 = Arow0 + (size_t)16 * DK;
#pragma unroll
    for (int k = 0; k < 16; ++k) {
      const bf16x8 af0 = *(const bf16x8*)(Arow0 + k * 32);
      const bf16x8 af1 = *(const bf16x8*)(Arow1 + k * 32);
      const bf16x8 bf0 = *(const bf16x8*)&Bs[c][k * 32 + q * 8];
      const bf16x8 bf1 = *(const bf16x8*)&Bs[16 + c][k * 32 + q * 8];
      acc[0][0] = __builtin_amdgcn_mfma_f32_16x16x32_bf16(af0, bf0, acc[0][0], 0, 0, 0);
      acc[0][1] = __builtin_amdgcn_mfma_f32_16x16x32_bf16(af0, bf1, acc[0][1], 0, 0, 0);
      acc[1][0] = __builtin_amdgcn_mfma_f32_16x16x32_bf16(af1, bf0, acc[1][0], 0, 0, 0);
      acc[1][1] = __builtin_amdgcn_mfma_f32_16x16x32_bf16(af1, bf1, acc[1][1], 0, 0, 0);
    }

    // ---- scan epilogue ----
    // acc[i][j][r] = z for t = t0 + wave*32 + i*16 + q*4 + r, col = n0 + j*16 + c
    f32x4 vloc[2][2];
    float icarry[2] = {0.f, 0.f};
#pragma unroll
    for (int i = 0; i < 2; ++i) {
#pragma unroll
      for (int j = 0; j < 2; ++j) {
        const float la2 = la2_j[j];
        f32x4 w;
#pragma unroll
        for (int r = 0; r < 4; ++r) {
          const int tp1 = t0 + wave * 32 + i * 16 + q * 4 + r + 1;
          const float z = acc[i][j][r] + bias_j[j];
          float inv = fminf(__builtin_amdgcn_exp2f(-la2 * (float)tp1), 1e12f);
          if (neg_j[j] && (tp1 & 1)) inv = 1e12f;
          w[r] = z * inv;
        }
        const float pr0 = w[0];
        const float pr1 = pr0 + w[1];
        const float pr2 = pr1 + w[2];
        const float pr3 = pr2 + w[3];
        const float x1 = __shfl_xor(pr3, 16, 64);  // q^1
        const float x2 = __shfl_xor(pr3, 32, 64);  // q^2
        const float x3 = __shfl_xor(pr3, 48, 64);  // q^3
        float sq = 0.f;
        if (q >= 2) sq += x2 + x3;
        if (q & 1) sq += x1;
        const float base = icarry[j] + sq;
        vloc[i][j] = (f32x4){base + pr0, base + pr1, base + pr2, base + pr3};
        icarry[j] += pr3 + x1 + x2 + x3;  // total over all 16 rows of frag i
      }
    }
    if (q == 0) {
#pragma unroll
      for (int j = 0; j < 2; ++j) chunkTot[wave][j * 16 + c] = icarry[j];
    }
    __syncthreads();

    // cross-wave carry for this wave's 32-row chunk (wave-uniform loop)
    float cc[2];
#pragma unroll
    for (int j = 0; j < 2; ++j) {
      float s = colCarry[mc & 1][j * 16 + c];
      for (int w2 = 0; w2 < wave; ++w2) s += chunkTot[w2][j * 16 + c];
      cc[j] = s;
    }
    // publish next chunk's carry into the OTHER buffer (no race with readers)
    if (tid < 32) {
      float s = colCarry[mc & 1][tid];
#pragma unroll
      for (int w2 = 0; w2 < 8; ++w2) s += chunkTot[w2][tid];
      colCarry[(mc + 1) & 1][tid] = s;
    }

    // phase 2: produce h, write out
#pragma unroll
    for (int i = 0; i < 2; ++i) {
#pragma unroll
      for (int j = 0; j < 2; ++j) {
        const float la2 = la2_j[j];
        const int col = n0 + j * 16 + c;
#pragma unroll
        for (int r = 0; r < 4; ++r) {
          const int tl = t0 + wave * 32 + i * 16 + q * 4 + r;
          const int tp1 = tl + 1;
          float pv = __builtin_amdgcn_exp2f(la2 * (float)tp1);
          if (neg_j[j] && (tp1 & 1)) pv = -pv;
          const float v = cc[j] + vloc[i][j][r];
          const float hv = pv * v + pv * h0_j[j];
          const float zval = acc[i][j][r] + bias_j[j];
          out[(size_t)(b * T_DIM + tl) * H_DIM + col] = zm_j[j] ? zval : hv;
        }
      }
    }
    __syncthreads();  // chunkTot reusable next m-chunk
  }
}

extern "C" void kernel_launch(void* const* d_in, const int* in_sizes, int n_in,
                              void* d_out, int out_size, void* d_ws, size_t ws_size,
                              hipStream_t stream) {
  const float* x     = (const float*)d_in[0];  // [B,T,DK]
  const float* h0    = (const float*)d_in[1];  // [B,H]
  const float* raw_a = (const float*)d_in[2];  // [H]
  const float* W     = (const float*)d_in[3];  // [H,DK]
  const float* bias  = (const float*)d_in[4];  // [H]
  float* out = (float*)d_out;                  // [B,T,H]

  char* ws = (char*)d_ws;
  __bf16* xb   = (__bf16*)(ws);                        // 16777216 B
  __bf16* wb   = (__bf16*)(ws + 16777216);             //  1048576 B
  float4* meta = (float4*)(ws + 16777216 + 1048576);   //    16384 B

  cvt_f32_bf16<<<(B_DIM * T_DIM * DK / 4 + 255) / 256, 256, 0, stream>>>(x, xb, B_DIM * T_DIM * DK / 4);
  cvt_f32_bf16<<<(H_DIM * DK / 4 + 255) / 256, 256, 0, stream>>>(W, wb, H_DIM * DK / 4);
  compute_meta<<<H_DIM / 256, 256, 0, stream>>>(raw_a, meta);
  fused_rnn<<<512, 512, 0, stream>>>(xb, wb, bias, meta, h0, out);
}

// Round 6
// 162.554 us; speedup vs baseline: 1.0001x; 1.0001x over previous
//
#include <hip/hip_runtime.h>
#include <cstdint>

// Problem dims (fixed by the reference)
#define B_DIM 16
#define T_DIM 1024
#define DK    512     // D_IN
#define H_DIM 1024
#define BST   516     // padded LDS leading dim for Bs (bank spread)

typedef __bf16 bf16x8 __attribute__((ext_vector_type(8)));
typedef __bf16 bf16x4 __attribute__((ext_vector_type(4)));
typedef float  f32x4  __attribute__((ext_vector_type(4)));

// ---- fp32 -> bf16 conversion, 4 elems/thread ----
__global__ __launch_bounds__(256) void cvt_f32_bf16(const float* __restrict__ in,
                                                    __bf16* __restrict__ out, int n4) {
  int i = blockIdx.x * 256 + threadIdx.x;
  if (i >= n4) return;
  f32x4 v = ((const f32x4*)in)[i];
  bf16x4 o;
  o.x = (__bf16)v.x; o.y = (__bf16)v.y; o.z = (__bf16)v.z; o.w = (__bf16)v.w;
  ((bf16x4*)out)[i] = o;
}

// ---- per-h meta: {a, log2|a|, neg?, zero-mask?} ----
__global__ __launch_bounds__(256) void compute_meta(const float* __restrict__ raw_a,
                                                    float4* __restrict__ meta) {
  int h = blockIdx.x * 256 + threadIdx.x;
  if (h >= H_DIM) return;
  float a = tanhf(raw_a[h]);
  float la2 = log2f(fabsf(a));   // a==0 -> -inf; exp2f(-inf)=0, handled by zero-mask
  meta[h] = make_float4(a, la2, (a < 0.f) ? 1.f : 0.f, (fabsf(a) < 1e-6f) ? 1.f : 0.f);
}

// ---- fully fused: GEMM (z = x W^T + b) + weighted cumsum scan + output ----
// Grid: 512 blocks = (b = bid&15) x (strip = bid>>4, 32 cols).
// Block: 512 thr, 8 waves. B-strip (32 cols x full K=512) resident in LDS;
// K-loop is BARRIER-FREE with an EXPLICIT depth-8 register prefetch pipeline
// on the A operand (global->VGPR, 16 loads in flight, fine-grained vmcnt).
// 4 sequential m-chunks of 256 t; wave w owns rows [w*32, w*32+32).
__global__ __launch_bounds__(512, 4) void fused_rnn(const __bf16* __restrict__ xb,  // [B*T, DK]
                                                    const __bf16* __restrict__ wb,  // [H, DK]
                                                    const float* __restrict__ bias, // [H]
                                                    const float4* __restrict__ meta,// [H]
                                                    const float* __restrict__ h0g,  // [B, H]
                                                    float* __restrict__ out) {      // [B*T, H]
  __shared__ __align__(16) __bf16 Bs[32][BST];   // 33 KB, whole K extent
  __shared__ float chunkTot[8][32];
  __shared__ float colCarry[2][32];

  const int tid  = threadIdx.x;
  const int wave = tid >> 6;   // 0..7
  const int lane = tid & 63;
  const int q = lane >> 4;     // 0..3
  const int c = lane & 15;     // 0..15

  const int b  = blockIdx.x & 15;
  const int n0 = (blockIdx.x >> 4) * 32;

  // per-lane column constants (2 cols per lane: j*16+c)
  float bias_j[2], la2_j[2], h0_j[2];
  bool neg_j[2], zm_j[2];
#pragma unroll
  for (int j = 0; j < 2; ++j) {
    const int col = n0 + j * 16 + c;
    bias_j[j] = bias[col];
    const float4 mt = meta[col];
    la2_j[j] = mt.y;
    neg_j[j] = mt.z != 0.f;
    zm_j[j]  = mt.w != 0.f;
    h0_j[j]  = h0g[(size_t)b * H_DIM + col];
  }

  // preload whole B strip: 512 thr = 32 cols x 16 k-chunks of 32
  {
    const int col = tid >> 4;
    const int kc  = tid & 15;
    const __bf16* gw = wb + (size_t)(n0 + col) * DK + kc * 32;
#pragma unroll
    for (int u = 0; u < 4; ++u)
      *(bf16x8*)&Bs[col][kc * 32 + u * 8] = *(const bf16x8*)(gw + u * 8);
  }
  if (tid < 32) colCarry[0][tid] = 0.f;
  __syncthreads();   // the ONLY barrier before the scan epilogues

  const __bf16* const xbB = xb + (size_t)b * T_DIM * DK;

  for (int mc = 0; mc < 4; ++mc) {
    const int t0 = mc * 256;

    f32x4 acc[2][2];
#pragma unroll
    for (int i = 0; i < 2; ++i)
#pragma unroll
      for (int j = 0; j < 2; ++j) acc[i][j] = (f32x4){0.f, 0.f, 0.f, 0.f};

    // barrier-free K-loop, explicit depth-8 A prefetch pipeline.
    const __bf16* const Arow0 = xbB + (size_t)(t0 + wave * 32 + c) * DK + q * 8;
    const __bf16* const Arow1 = Arow0 + (size_t)16 * DK;

    bf16x8 a0b[8], a1b[8];
#pragma unroll
    for (int s = 0; s < 8; ++s) {
      a0b[s] = *(const bf16x8*)(Arow0 + s * 32);   // base + imm offsets, 16 in flight
      a1b[s] = *(const bf16x8*)(Arow1 + s * 32);
    }
#pragma unroll
    for (int k = 0; k < 16; ++k) {
      const bf16x8 af0 = a0b[k & 7];
      const bf16x8 af1 = a1b[k & 7];
      if (k < 8) {   // reissue the slot for the back half
        a0b[k] = *(const bf16x8*)(Arow0 + (k + 8) * 32);
        a1b[k] = *(const bf16x8*)(Arow1 + (k + 8) * 32);
      }
      const bf16x8 bf0 = *(const bf16x8*)&Bs[c][k * 32 + q * 8];
      const bf16x8 bf1 = *(const bf16x8*)&Bs[16 + c][k * 32 + q * 8];
      acc[0][0] = __builtin_amdgcn_mfma_f32_16x16x32_bf16(af0, bf0, acc[0][0], 0, 0, 0);
      acc[0][1] = __builtin_amdgcn_mfma_f32_16x16x32_bf16(af0, bf1, acc[0][1], 0, 0, 0);
      acc[1][0] = __builtin_amdgcn_mfma_f32_16x16x32_bf16(af1, bf0, acc[1][0], 0, 0, 0);
      acc[1][1] = __builtin_amdgcn_mfma_f32_16x16x32_bf16(af1, bf1, acc[1][1], 0, 0, 0);
    }

    // ---- scan epilogue ----
    // acc[i][j][r] = z for t = t0 + wave*32 + i*16 + q*4 + r, col = n0 + j*16 + c
    f32x4 vloc[2][2];
    float icarry[2] = {0.f, 0.f};
#pragma unroll
    for (int i = 0; i < 2; ++i) {
#pragma unroll
      for (int j = 0; j < 2; ++j) {
        const float la2 = la2_j[j];
        f32x4 w;
#pragma unroll
        for (int r = 0; r < 4; ++r) {
          const int tp1 = t0 + wave * 32 + i * 16 + q * 4 + r + 1;
          const float z = acc[i][j][r] + bias_j[j];
          float inv = fminf(__builtin_amdgcn_exp2f(-la2 * (float)tp1), 1e12f);
          if (neg_j[j] && (tp1 & 1)) inv = 1e12f;
          w[r] = z * inv;
        }
        const float pr0 = w[0];
        const float pr1 = pr0 + w[1];
        const float pr2 = pr1 + w[2];
        const float pr3 = pr2 + w[3];
        const float x1 = __shfl_xor(pr3, 16, 64);  // q^1
        const float x2 = __shfl_xor(pr3, 32, 64);  // q^2
        const float x3 = __shfl_xor(pr3, 48, 64);  // q^3
        float sq = 0.f;
        if (q >= 2) sq += x2 + x3;
        if (q & 1) sq += x1;
        const float base = icarry[j] + sq;
        vloc[i][j] = (f32x4){base + pr0, base + pr1, base + pr2, base + pr3};
        icarry[j] += pr3 + x1 + x2 + x3;  // total over all 16 rows of frag i
      }
    }
    if (q == 0) {
#pragma unroll
      for (int j = 0; j < 2; ++j) chunkTot[wave][j * 16 + c] = icarry[j];
    }
    __syncthreads();

    // cross-wave carry for this wave's 32-row chunk (wave-uniform loop)
    float cc[2];
#pragma unroll
    for (int j = 0; j < 2; ++j) {
      float s = colCarry[mc & 1][j * 16 + c];
      for (int w2 = 0; w2 < wave; ++w2) s += chunkTot[w2][j * 16 + c];
      cc[j] = s;
    }
    // publish next chunk's carry into the OTHER buffer (no race with readers)
    if (tid < 32) {
      float s = colCarry[mc & 1][tid];
#pragma unroll
      for (int w2 = 0; w2 < 8; ++w2) s += chunkTot[w2][tid];
      colCarry[(mc + 1) & 1][tid] = s;
    }

    // phase 2: produce h, write out
#pragma unroll
    for (int i = 0; i < 2; ++i) {
#pragma unroll
      for (int j = 0; j < 2; ++j) {
        const float la2 = la2_j[j];
        const int col = n0 + j * 16 + c;
#pragma unroll
        for (int r = 0; r < 4; ++r) {
          const int tl = t0 + wave * 32 + i * 16 + q * 4 + r;
          const int tp1 = tl + 1;
          float pv = __builtin_amdgcn_exp2f(la2 * (float)tp1);
          if (neg_j[j] && (tp1 & 1)) pv = -pv;
          const float v = cc[j] + vloc[i][j][r];
          const float hv = pv * v + pv * h0_j[j];
          const float zval = acc[i][j][r] + bias_j[j];
          out[(size_t)(b * T_DIM + tl) * H_DIM + col] = zm_j[j] ? zval : hv;
        }
      }
    }
    __syncthreads();  // chunkTot reusable next m-chunk
  }
}

extern "C" void kernel_launch(void* const* d_in, const int* in_sizes, int n_in,
                              void* d_out, int out_size, void* d_ws, size_t ws_size,
                              hipStream_t stream) {
  const float* x     = (const float*)d_in[0];  // [B,T,DK]
  const float* h0    = (const float*)d_in[1];  // [B,H]
  const float* raw_a = (const float*)d_in[2];  // [H]
  const float* W     = (const float*)d_in[3];  // [H,DK]
  const float* bias  = (const float*)d_in[4];  // [H]
  float* out = (float*)d_out;                  // [B,T,H]

  char* ws = (char*)d_ws;
  __bf16* xb   = (__bf16*)(ws);                        // 16777216 B
  __bf16* wb   = (__bf16*)(ws + 16777216);             //  1048576 B
  float4* meta = (float4*)(ws + 16777216 + 1048576);   //    16384 B

  cvt_f32_bf16<<<(B_DIM * T_DIM * DK / 4 + 255) / 256, 256, 0, stream>>>(x, xb, B_DIM * T_DIM * DK / 4);
  cvt_f32_bf16<<<(H_DIM * DK / 4 + 255) / 256, 256, 0, stream>>>(W, wb, H_DIM * DK / 4);
  compute_meta<<<H_DIM / 256, 256, 0, stream>>>(raw_a, meta);
  fused_rnn<<<512, 512, 0, stream>>>(xb, wb, bias, meta, h0, out);
}